// Round 10
// baseline (8464.736 us; speedup 1.0000x reference)
//
#include <hip/hip_runtime.h>

#define NN 4096
#define TT 12
#define CC 32
#define WW 10            // T-2 windows
#define K3 12288         // 3*N
#define NCOL 640         // B*W*C
#define SA 4096.0f       // adj scale (2^12)
#define SX 1024.0f       // activation scale (2^10)
#define BMT 128          // block m-tile
#define BNT 128          // block n-tile
#define BK 32
#define NT (K3 / BK)     // 384 k-steps

typedef _Float16 half8 __attribute__((ext_vector_type(8)));
typedef _Float16 half4_t __attribute__((ext_vector_type(4)));
typedef float floatx4 __attribute__((ext_vector_type(4)));

// ---------------- adj fp32 -> fp16 (scaled, row-major) ----------------
__global__ void k_conv_adj(const float* __restrict__ adj, _Float16* __restrict__ a16) {
    long n4 = (long)K3 * K3 / 4;
    long i = (long)blockIdx.x * blockDim.x + threadIdx.x;
    long stride = (long)gridDim.x * blockDim.x;
    const float4* src = (const float4*)adj;
    half4_t* dst = (half4_t*)a16;
    for (; i < n4; i += stride) {
        float4 v = src[i];
        half4_t h;
        h[0] = (_Float16)(v.x * SA);
        h[1] = (_Float16)(v.y * SA);
        h[2] = (_Float16)(v.z * SA);
        h[3] = (_Float16)(v.w * SA);
        dst[i] = h;
    }
}

// ---------------- build X0^T [NCOL][K3] fp16 (row-major) ----------------
__global__ void k_prep(const float* __restrict__ data, const float* __restrict__ temb,
                       const float* __restrict__ semb, _Float16* __restrict__ x0t) {
    __shared__ float sb[CC][64 + 1];
    int z = blockIdx.y;                 // 0..59
    int b = z / 30; int r = z % 30; int w = r / 3; int j = r % 3;
    int t = w + j;
    int n0 = blockIdx.x * 64;
    int tid = threadIdx.x;
    for (int e = tid; e < 64 * CC; e += 256) {
        int nl = e >> 5, c = e & 31;
        float v = data[((long)(b * TT + t) * NN + n0 + nl) * CC + c]
                + temb[t * CC + c] + semb[(n0 + nl) * CC + c];
        sb[c][nl] = v;
    }
    __syncthreads();
    int bw = b * WW + w;
    for (int e = tid; e < 64 * CC; e += 256) {
        int c = e >> 6, nl = e & 63;
        x0t[(long)(bw * CC + c) * K3 + j * NN + n0 + nl] = (_Float16)sb[c][nl];
    }
}

__device__ __forceinline__ void gload_lds16(const _Float16* g, _Float16* l) {
    __builtin_amdgcn_global_load_lds(
        (const __attribute__((address_space(1))) void*)g,
        (__attribute__((address_space(3))) void*)l, 16, 0, 0);
}

// ---------------- m97-structure GEMM (128x128, BK=32) + fused W-GEMM/GLU ----------
// 256 thr / 4 waves (2x2); wave (wm,wn) owns 64x64 (4x4 frags). LDS: 2x16KB dbuf.
// One __syncthreads per K-step (vmcnt+lgkm drain), STAGE issued before ds_read.
template <int MODE>
__global__ __launch_bounds__(256, 2) void k_gemm_glu(
    const _Float16* __restrict__ A, const _Float16* __restrict__ BT,
    const float* __restrict__ Wt, const float* __restrict__ bias,
    _Float16* __restrict__ outH,
    const _Float16* __restrict__ x1, const _Float16* __restrict__ x2,
    float* __restrict__ outF,
    float invS, int mBase)
{
    // buffer: [0..4096) A-tile 128x32, [4096..8192) B-tile 128x32
    __shared__ __attribute__((aligned(16))) _Float16 AB[2][8192];   // 32 KB
    __shared__ float WB[CC * 64 + 64];                              // 8.4 KB

    int tid = threadIdx.x;
    int lane = tid & 63, wid = tid >> 6;
    int wm = wid >> 1, wn = wid & 1;

    // bijective XCD-chunked swizzle; 5 n-tiles of one A-panel adjacent on one XCD
    int nblk = gridDim.x;
    int q = nblk >> 3, r = nblk & 7;
    int xcd = blockIdx.x & 7, bi = blockIdx.x >> 3;
    int lin = (xcd < r ? xcd * (q + 1) : r * (q + 1) + (xcd - r) * q) + bi;
    int mt = lin / 5, nt = lin - mt * 5;
    long m0 = (long)mt * BMT;
    int n0 = nt * BNT;

    for (int e = tid; e < CC * 64; e += 256) WB[e] = Wt[e];
    if (tid < 64) WB[CC * 64 + tid] = bias[tid];

    // staging sources: chunk ci -> row=ci>>2, kb=ci&3, swizzled ks = kb ^ ((row>>1)&3)
    int rowS = tid >> 2, kbS = tid & 3;
    int ksS = kbS ^ ((rowS >> 1) & 3);
    const _Float16* aS = A + (long)(mBase + m0 + rowS) * K3 + ksS * 8;
    const _Float16* bS = BT + (long)(n0 + rowS) * K3 + ksS * 8;

#define STAGE(bufi, kOff)                                            \
    do {                                                             \
        _Float16* bp = &AB[bufi][0];                                 \
        gload_lds16(aS + (kOff),            bp + wid * 512);         \
        gload_lds16(aS + 64 * K3 + (kOff),  bp + 2048 + wid * 512);  \
        gload_lds16(bS + (kOff),            bp + 4096 + wid * 512);  \
        gload_lds16(bS + 64 * K3 + (kOff),  bp + 6144 + wid * 512);  \
    } while (0)

    // fragment read offsets (halves), swizzle-matched: kbs invariant under row+=16/64
    int fr = lane & 15, kq = lane >> 4;
    int kbs = kq ^ ((fr >> 1) & 3);
    int aOff[4], bOff[4];
#pragma unroll
    for (int ms = 0; ms < 4; ++ms) aOff[ms] = (wm * 64 + ms * 16 + fr) * 32 + kbs * 8;
#pragma unroll
    for (int ns = 0; ns < 4; ++ns) bOff[ns] = 4096 + (wn * 64 + ns * 16 + fr) * 32 + kbs * 8;

    floatx4 acc[4][4] = {};

    STAGE(0, 0);
    __syncthreads();

    int cur = 0;
#pragma unroll 1
    for (int t = 0; t < NT; ++t) {
        if (t + 1 < NT) STAGE(cur ^ 1, (long)(t + 1) * BK);
        const _Float16* P = &AB[cur][0];
        half8 af[4], bf[4];
#pragma unroll
        for (int ms = 0; ms < 4; ++ms) af[ms] = *(const half8*)(P + aOff[ms]);
#pragma unroll
        for (int ns = 0; ns < 4; ++ns) bf[ns] = *(const half8*)(P + bOff[ns]);
#pragma unroll
        for (int ms = 0; ms < 4; ++ms)
#pragma unroll
            for (int ns = 0; ns < 4; ++ns)
                acc[ms][ns] = __builtin_amdgcn_mfma_f32_16x16x32_f16(af[ms], bf[ns], acc[ms][ns], 0, 0, 0);
        __syncthreads();          // drains vmcnt(0)+lgkmcnt(0): tile t+1 landed, reads done
        cur ^= 1;
    }
#undef STAGE

    // -------- epilogue: 4 passes of 32 cols; LDS transpose + W-GEMM + GLU --------
    float* scr = (float*)AB;          // 128 x 33 floats = 16.9 KB <= 32 KB
    const int SW = 33;
    int rb = (lane >> 4) * 4, cb = lane & 15;

#pragma unroll 1
    for (int p = 0; p < 4; ++p) {
        __syncthreads();
        if (wn == (p >> 1)) {
            int nsb = (p & 1) * 2;
#pragma unroll
            for (int ms = 0; ms < 4; ++ms)
#pragma unroll
                for (int nsi = 0; nsi < 2; ++nsi)
#pragma unroll
                    for (int i = 0; i < 4; ++i)
                        scr[(wm * 64 + ms * 16 + rb + i) * SW + nsi * 16 + cb] = acc[ms][nsb + nsi][i];
        }
        __syncthreads();
        int m = tid >> 1, half = tid & 1;
        int bw = nt * 4 + p;
        long mg = m0 + m;
        float g[CC];
#pragma unroll
        for (int c = 0; c < CC; ++c) g[c] = scr[m * SW + c] * invS;
        float y0[16], y1[16];
#pragma unroll
        for (int o = 0; o < 16; ++o) {
            y0[o] = WB[CC * 64 + half * 16 + o];
            y1[o] = WB[CC * 64 + 32 + half * 16 + o];
        }
#pragma unroll
        for (int c = 0; c < CC; ++c) {
            float gv = g[c];
#pragma unroll
            for (int o = 0; o < 16; ++o) {
                y0[o] = fmaf(gv, WB[c * 64 + half * 16 + o], y0[o]);
                y1[o] = fmaf(gv, WB[c * 64 + 32 + half * 16 + o], y1[o]);
            }
        }
        if (MODE == 0) {
#pragma unroll
            for (int o = 0; o < 16; ++o) {
                float rr = y0[o] * (1.f / (1.f + __expf(-y1[o])));
                outH[(long)(bw * CC + half * 16 + o) * K3 + mg] = (_Float16)(rr * SX);
            }
        } else {
            float res[16];
#pragma unroll
            for (int o = 0; o < 16; ++o) {
                float rr = y0[o] * (1.f / (1.f + __expf(-y1[o])));
                long idx = (long)(bw * CC + half * 16 + o) * K3 + NN + mg;
                float v1 = (float)x1[idx] * (1.f / SX);
                float v2 = (float)x2[idx] * (1.f / SX);
                res[o] = fmaxf(rr, fmaxf(v1, v2));
            }
            float4* op = (float4*)(outF + ((long)bw * NN + mg) * CC + half * 16);
#pragma unroll
            for (int qv = 0; qv < 4; ++qv)
                op[qv] = make_float4(res[qv * 4 + 0], res[qv * 4 + 1],
                                     res[qv * 4 + 2], res[qv * 4 + 3]);
        }
    }
}

extern "C" void kernel_launch(void* const* d_in, const int* in_sizes, int n_in,
                              void* d_out, int out_size, void* d_ws, size_t ws_size,
                              hipStream_t stream)
{
    const float* data = (const float*)d_in[0];
    const float* adj  = (const float*)d_in[1];
    const float* temb = (const float*)d_in[2];
    const float* semb = (const float*)d_in[3];
    const float* W0 = (const float*)d_in[4];
    const float* b0 = (const float*)d_in[5];
    const float* W1 = (const float*)d_in[6];
    const float* b1 = (const float*)d_in[7];
    const float* W2 = (const float*)d_in[8];
    const float* b2 = (const float*)d_in[9];
    float* out = (float*)d_out;
    (void)ws_size; (void)in_sizes; (void)n_in; (void)out_size;

    char* ws = (char*)d_ws;
    _Float16* A16 = (_Float16*)ws;  ws += (size_t)K3 * K3 * 2;        // 302 MB
    _Float16* X0  = (_Float16*)ws;  ws += (size_t)NCOL * K3 * 2;      // 15.7 MB
    _Float16* X1  = (_Float16*)ws;  ws += (size_t)NCOL * K3 * 2;
    _Float16* X2  = (_Float16*)ws;  ws += (size_t)NCOL * K3 * 2;

    k_conv_adj<<<4096, 256, 0, stream>>>(adj, A16);
    k_prep<<<dim3(64, 60), 256, 0, stream>>>(data, temb, semb, X0);

    // layer 1: 96 m-tiles x 5 n-tiles = 480 blocks
    k_gemm_glu<0><<<480, 256, 0, stream>>>(A16, X0, W0, b0, X1,
                                           nullptr, nullptr, nullptr, 1.f / SA, 0);
    // layer 2
    k_gemm_glu<0><<<480, 256, 0, stream>>>(A16, X1, W1, b1, X2,
                                           nullptr, nullptr, nullptr, 1.f / (SA * SX), 0);
    // layer 3: middle N rows (32 m-tiles x 5 = 160 blocks), fused GLU+max+output
    k_gemm_glu<1><<<160, 256, 0, stream>>>(A16, X2, W2, b2, nullptr,
                                           X1, X2, out, 1.f / (SA * SX), NN);
}